// Round 2
// baseline (3603.233 us; speedup 1.0000x reference)
//
#include <hip/hip_runtime.h>

#define NH 4     // heads
#define CH 64    // channels/head

// ---------------- encoder: h = relu(x @ W + b); x:[N,8], W:[8,64] ----------------
__global__ void encoder_kernel(const float* __restrict__ x, const float* __restrict__ W,
                               const float* __restrict__ b, float* __restrict__ h, int N) {
  int idx = blockIdx.x * blockDim.x + threadIdx.x;
  if (idx >= N * 64) return;
  int n = idx >> 6, j = idx & 63;
  const float* xp = x + n * 8;
  float acc = b[j];
#pragma unroll
  for (int k = 0; k < 8; ++k) acc = fmaf(xp[k], W[k * 64 + j], acc);
  h[idx] = fmaxf(acc, 0.0f);
}

// ---------------- xl = h@Wl + bl, xr = h@Wr + br; h:[N,K], W:[K,256] ----------------
template <int K>
__global__ void lin_lr_kernel(const float* __restrict__ h,
                              const float* __restrict__ Wl, const float* __restrict__ bl,
                              const float* __restrict__ Wr, const float* __restrict__ br,
                              float* __restrict__ xl, float* __restrict__ xr, int N) {
  __shared__ float hs[8][K];
  int n0 = blockIdx.x * 8;
  int j = threadIdx.x;  // output column
  int nmax = N - n0; if (nmax > 8) nmax = 8;
  for (int idx = j; idx < nmax * K; idx += 256) {
    int m = idx / K, k = idx % K;
    hs[m][k] = h[(size_t)(n0 + m) * K + k];
  }
  __syncthreads();
  float accl[8], accr[8];
  float bjl = bl[j], bjr = br[j];
#pragma unroll
  for (int m = 0; m < 8; ++m) { accl[m] = bjl; accr[m] = bjr; }
  for (int k = 0; k < K; ++k) {
    float wl = Wl[k * 256 + j];
    float wr = Wr[k * 256 + j];
#pragma unroll
    for (int m = 0; m < 8; ++m) {
      accl[m] = fmaf(hs[m][k], wl, accl[m]);
      accr[m] = fmaf(hs[m][k], wr, accr[m]);
    }
  }
  for (int m = 0; m < nmax; ++m) {
    xl[(size_t)(n0 + m) * 256 + j] = accl[m];
    xr[(size_t)(n0 + m) * 256 + j] = accr[m];
  }
}

// ---------------- CSR build (counting sort by dst) ----------------
__global__ void hist_kernel(const int* __restrict__ dst, int* __restrict__ deg, int E) {
  int e = blockIdx.x * blockDim.x + threadIdx.x;
  if (e < E) atomicAdd(&deg[dst[e]], 1);
}

// single-block exclusive scan: rowptr[i]=cursor[i]=excl_sum(deg[0..i)), rowptr[N]=E
__global__ void scan_kernel(const int* __restrict__ deg, int* __restrict__ rowptr,
                            int* __restrict__ cursor, int N, int E) {
  __shared__ int tmp[256];
  __shared__ int carry;
  int t = threadIdx.x;
  if (t == 0) carry = 0;
  __syncthreads();
  for (int base = 0; base < N; base += 256) {
    int i = base + t;
    int v = (i < N) ? deg[i] : 0;
    tmp[t] = v;
    __syncthreads();
#pragma unroll
    for (int off = 1; off < 256; off <<= 1) {
      int add = (t >= off) ? tmp[t - off] : 0;
      __syncthreads();
      tmp[t] += add;
      __syncthreads();
    }
    int c0 = carry;
    if (i < N) { int ex = c0 + tmp[t] - v; rowptr[i] = ex; cursor[i] = ex; }
    __syncthreads();
    if (t == 0) carry = c0 + tmp[255];
    __syncthreads();
  }
  if (t == 0) rowptr[N] = E;
}

__global__ void scatter_build_kernel(const int* __restrict__ src, const int* __restrict__ dst,
                                     const float* __restrict__ ea, int* __restrict__ cursor,
                                     int* __restrict__ srcs, float* __restrict__ eas, int E) {
  int e = blockIdx.x * blockDim.x + threadIdx.x;
  if (e >= E) return;
  int d = dst[e];
  int pos = atomicAdd(&cursor[d], 1);
  srcs[pos] = src[e];
  eas[pos] = ea[e];
}

// ---------------- fused GATv2: alpha + softmax + aggregate + bias + relu ----------------
// One wave per node. Lane l owns channels 4l..4l+3 (head = l>>4).
// alpha_e = dot(att_h, leaky(xl[src_e] + xr[d] + ea_e*We)); no max-subtraction
// (|alpha| << 85, exp cannot overflow); out = (sum ex*xl)/(sum ex) + bias, relu.
__device__ __forceinline__ void edge_accum(const float4 xlv, const float eav,
                                           const float4 xr4, const float4 We4, const float4 at4,
                                           float4& acc, float& denom) {
  float4 v;
  v.x = fmaf(eav, We4.x, xlv.x + xr4.x);
  v.y = fmaf(eav, We4.y, xlv.y + xr4.y);
  v.z = fmaf(eav, We4.z, xlv.z + xr4.z);
  v.w = fmaf(eav, We4.w, xlv.w + xr4.w);
  v.x = (v.x >= 0.f) ? v.x : 0.2f * v.x;
  v.y = (v.y >= 0.f) ? v.y : 0.2f * v.y;
  v.z = (v.z >= 0.f) ? v.z : 0.2f * v.z;
  v.w = (v.w >= 0.f) ? v.w : 0.2f * v.w;
  float p = v.x * at4.x + v.y * at4.y + v.z * at4.z + v.w * at4.w;
  p += __shfl_xor(p, 1, 64);
  p += __shfl_xor(p, 2, 64);
  p += __shfl_xor(p, 4, 64);
  p += __shfl_xor(p, 8, 64);   // now all 16 lanes of the head group hold alpha_h
  float ex = __expf(p);
  denom += ex;
  acc.x = fmaf(ex, xlv.x, acc.x);
  acc.y = fmaf(ex, xlv.y, acc.y);
  acc.z = fmaf(ex, xlv.z, acc.z);
  acc.w = fmaf(ex, xlv.w, acc.w);
}

template <bool POOL>
__global__ void gat_aggregate_kernel(const int* __restrict__ rowptr,
                                     const int* __restrict__ srcs,
                                     const float* __restrict__ eas,
                                     const float* __restrict__ xl,
                                     const float* __restrict__ xr,
                                     const float* __restrict__ We,
                                     const float* __restrict__ att,
                                     const float* __restrict__ bias,
                                     float* __restrict__ out,
                                     const int* __restrict__ batch,
                                     float* __restrict__ sums,
                                     float* __restrict__ cnt,
                                     int N) {
  int d = (int)((blockIdx.x * (size_t)blockDim.x + threadIdx.x) >> 6);
  int lane = threadIdx.x & 63;
  if (d >= N) return;
  const float4* xl4p = (const float4*)xl;
  float4 xr4 = ((const float4*)xr)[(size_t)d * 64 + lane];
  float4 We4 = ((const float4*)We)[lane];
  float4 at4 = ((const float4*)att)[lane];
  int beg = rowptr[d], end = rowptr[d + 1];
  float4 acc = {0.f, 0.f, 0.f, 0.f};
  float denom = 0.f;
  int i = beg;
  for (; i + 1 < end; i += 2) {     // 2x unroll: two gathers in flight
    int s0 = srcs[i], s1 = srcs[i + 1];
    float e0 = eas[i], e1 = eas[i + 1];
    float4 a0 = xl4p[(size_t)s0 * 64 + lane];
    float4 a1 = xl4p[(size_t)s1 * 64 + lane];
    edge_accum(a0, e0, xr4, We4, at4, acc, denom);
    edge_accum(a1, e1, xr4, We4, at4, acc, denom);
  }
  if (i < end) {
    int s0 = srcs[i];
    float e0 = eas[i];
    float4 a0 = xl4p[(size_t)s0 * 64 + lane];
    edge_accum(a0, e0, xr4, We4, at4, acc, denom);
  }
  float inv = 1.f / (denom + 1e-16f);
  float4 b4 = ((const float4*)bias)[lane];
  float4 o;
  o.x = fmaxf(fmaf(acc.x, inv, b4.x), 0.f);
  o.y = fmaxf(fmaf(acc.y, inv, b4.y), 0.f);
  o.z = fmaxf(fmaf(acc.z, inv, b4.z), 0.f);
  o.w = fmaxf(fmaf(acc.w, inv, b4.w), 0.f);
  if (POOL) {
    int g = batch[d];
    float* sg = sums + (size_t)g * 256 + lane * 4;
    atomicAdd(sg + 0, o.x);
    atomicAdd(sg + 1, o.y);
    atomicAdd(sg + 2, o.z);
    atomicAdd(sg + 3, o.w);
    if (lane == 0) atomicAdd(&cnt[g], 1.0f);
  } else {
    ((float4*)out)[(size_t)d * 64 + lane] = o;
  }
}

// ---------------- per-graph MLP head ----------------
__global__ void mlp_kernel(const float* __restrict__ sums, const float* __restrict__ cnt,
                           const float* __restrict__ p1W, const float* __restrict__ p1b,
                           const float* __restrict__ lng, const float* __restrict__ lnb,
                           const float* __restrict__ p2W, const float* __restrict__ p2b,
                           float* __restrict__ outp, int G) {
  __shared__ float p[256];
  __shared__ float z[128];
  __shared__ float wsum[2];
  __shared__ float wsum2[2];
  int g = blockIdx.x;
  int t = threadIdx.x;  // 0..127
  float c = fmaxf(cnt[g], 1.0f);
  p[t] = sums[(size_t)g * 256 + t] / c;
  p[t + 128] = sums[(size_t)g * 256 + t + 128] / c;
  __syncthreads();
  float acc = p1b[t];
  for (int k = 0; k < 256; ++k) acc = fmaf(p[k], p1W[k * 128 + t], acc);
  float v = acc;
#pragma unroll
  for (int off = 32; off > 0; off >>= 1) v += __shfl_xor(v, off, 64);
  if ((t & 63) == 0) wsum[t >> 6] = v;
  __syncthreads();
  float mu = (wsum[0] + wsum[1]) * (1.0f / 128.0f);
  float dv = acc - mu;
  float vv = dv * dv;
#pragma unroll
  for (int off = 32; off > 0; off >>= 1) vv += __shfl_xor(vv, off, 64);
  if ((t & 63) == 0) wsum2[t >> 6] = vv;
  __syncthreads();
  float var = (wsum2[0] + wsum2[1]) * (1.0f / 128.0f);
  float zv = dv * rsqrtf(var + 1e-5f) * lng[t] + lnb[t];
  z[t] = fmaxf(zv, 0.0f);
  __syncthreads();
  if (t < 64) {
    float o = p2b[t];
    for (int k = 0; k < 128; ++k) o = fmaf(z[k], p2W[k * 64 + t], o);
    outp[(size_t)g * 64 + t] = fmaxf(o, 0.0f);
  }
}

extern "C" void kernel_launch(void* const* d_in, const int* in_sizes, int n_in,
                              void* d_out, int out_size, void* d_ws, size_t ws_size,
                              hipStream_t stream) {
  const float* x      = (const float*)d_in[0];
  const int*   ei     = (const int*)d_in[1];
  const float* ea     = (const float*)d_in[2];
  const int*   batch  = (const int*)d_in[3];
  const float* enc_W  = (const float*)d_in[4];
  const float* enc_b  = (const float*)d_in[5];
  const float* Wl1    = (const float*)d_in[6];
  const float* bl1    = (const float*)d_in[7];
  const float* Wr1    = (const float*)d_in[8];
  const float* br1    = (const float*)d_in[9];
  const float* We1    = (const float*)d_in[10];
  const float* att1   = (const float*)d_in[11];
  const float* bias1  = (const float*)d_in[12];
  const float* Wl2    = (const float*)d_in[13];
  const float* bl2    = (const float*)d_in[14];
  const float* Wr2    = (const float*)d_in[15];
  const float* br2    = (const float*)d_in[16];
  const float* We2    = (const float*)d_in[17];
  const float* att2   = (const float*)d_in[18];
  const float* bias2  = (const float*)d_in[19];
  const float* p1W    = (const float*)d_in[20];
  const float* p1b    = (const float*)d_in[21];
  const float* lng    = (const float*)d_in[22];
  const float* lnb    = (const float*)d_in[23];
  const float* p2W    = (const float*)d_in[24];
  const float* p2b    = (const float*)d_in[25];
  float* outp = (float*)d_out;

  int N = in_sizes[0] / 8;
  int E = in_sizes[2];
  int G = out_size / 64;
  const int* src = ei;
  const int* dst = ei + E;

  // workspace layout
  float* ws     = (float*)d_ws;
  float* h0     = ws;                         // N*64
  float* B0     = h0     + (size_t)N * 64;    // N*256 (xl)
  float* B1     = B0     + (size_t)N * 256;   // N*256 (xr)
  float* B2     = B1     + (size_t)N * 256;   // N*256 (layer1 out)
  float* eas    = B2     + (size_t)N * 256;   // E floats (sorted edge attr)
  float* sums   = eas    + (size_t)E;         // G*256
  float* cnt    = sums   + (size_t)G * 256;   // G
  int*   srcs   = (int*)(cnt + G);            // E ints (sorted src)
  int*   rowptr = srcs + (size_t)E;           // N+1
  int*   cursor = rowptr + (size_t)(N + 1);   // N (doubles as deg histogram)

  // encoder
  encoder_kernel<<<(N * 64 + 255) / 256, 256, 0, stream>>>(x, enc_W, enc_b, h0, N);

  // CSR build (shared by both layers — dst is static)
  hipMemsetAsync(cursor, 0, (size_t)N * sizeof(int), stream);
  hist_kernel<<<(E + 255) / 256, 256, 0, stream>>>(dst, cursor, E);
  scan_kernel<<<1, 256, 0, stream>>>(cursor, rowptr, cursor, N, E);
  scatter_build_kernel<<<(E + 255) / 256, 256, 0, stream>>>(src, dst, ea, cursor, srcs, eas, E);

  // GAT layer 1 (K=64): h0 -> B2
  lin_lr_kernel<64><<<(N + 7) / 8, 256, 0, stream>>>(h0, Wl1, bl1, Wr1, br1, B0, B1, N);
  gat_aggregate_kernel<false><<<(N + 3) / 4, 256, 0, stream>>>(
      rowptr, srcs, eas, B0, B1, We1, att1, bias1, B2, nullptr, nullptr, nullptr, N);

  // GAT layer 2 (K=256): B2 -> pooled sums directly
  lin_lr_kernel<256><<<(N + 7) / 8, 256, 0, stream>>>(B2, Wl2, bl2, Wr2, br2, B0, B1, N);
  hipMemsetAsync(sums, 0, ((size_t)G * 256 + G) * sizeof(float), stream);
  gat_aggregate_kernel<true><<<(N + 3) / 4, 256, 0, stream>>>(
      rowptr, srcs, eas, B0, B1, We2, att2, bias2, nullptr, batch, sums, cnt, N);

  // per-graph MLP
  mlp_kernel<<<G, 128, 0, stream>>>(sums, cnt, p1W, p1b, lng, lnb, p2W, p2b, outp, G);
}

// Round 3
// 1035.548 us; speedup vs baseline: 3.4795x; 3.4795x over previous
//
#include <hip/hip_runtime.h>

#define NH 4     // heads
#define CH 64    // channels/head

// ---------------- encoder: h = relu(x @ W + b); x:[N,8], W:[8,64] ----------------
__global__ void encoder_kernel(const float* __restrict__ x, const float* __restrict__ W,
                               const float* __restrict__ b, float* __restrict__ h, int N) {
  int idx = blockIdx.x * blockDim.x + threadIdx.x;
  if (idx >= N * 64) return;
  int n = idx >> 6, j = idx & 63;
  const float* xp = x + n * 8;
  float acc = b[j];
#pragma unroll
  for (int k = 0; k < 8; ++k) acc = fmaf(xp[k], W[k * 64 + j], acc);
  h[idx] = fmaxf(acc, 0.0f);
}

// ---------------- xl = h@Wl + bl, xr = h@Wr + br; h:[N,K], W:[K,256] ----------------
template <int K>
__global__ void lin_lr_kernel(const float* __restrict__ h,
                              const float* __restrict__ Wl, const float* __restrict__ bl,
                              const float* __restrict__ Wr, const float* __restrict__ br,
                              float* __restrict__ xl, float* __restrict__ xr, int N) {
  __shared__ float hs[8][K];
  int n0 = blockIdx.x * 8;
  int j = threadIdx.x;  // output column
  int nmax = N - n0; if (nmax > 8) nmax = 8;
  for (int idx = j; idx < nmax * K; idx += 256) {
    int m = idx / K, k = idx % K;
    hs[m][k] = h[(size_t)(n0 + m) * K + k];
  }
  __syncthreads();
  float accl[8], accr[8];
  float bjl = bl[j], bjr = br[j];
#pragma unroll
  for (int m = 0; m < 8; ++m) { accl[m] = bjl; accr[m] = bjr; }
  for (int k = 0; k < K; ++k) {
    float wl = Wl[k * 256 + j];
    float wr = Wr[k * 256 + j];
#pragma unroll
    for (int m = 0; m < 8; ++m) {
      accl[m] = fmaf(hs[m][k], wl, accl[m]);
      accr[m] = fmaf(hs[m][k], wr, accr[m]);
    }
  }
  for (int m = 0; m < nmax; ++m) {
    xl[(size_t)(n0 + m) * 256 + j] = accl[m];
    xr[(size_t)(n0 + m) * 256 + j] = accr[m];
  }
}

// ---------------- CSR build (counting sort by dst), fully parallel scan ----------------
__global__ void hist_kernel(const int* __restrict__ dst, int* __restrict__ deg, int E) {
  int e = blockIdx.x * blockDim.x + threadIdx.x;
  if (e < E) atomicAdd(&deg[dst[e]], 1);
}

// A: per-block sum of 256 deg entries
__global__ void scan_partial_kernel(const int* __restrict__ deg, int* __restrict__ partial, int N) {
  __shared__ int sm[256];
  int t = threadIdx.x;
  int i = blockIdx.x * 256 + t;
  sm[t] = (i < N) ? deg[i] : 0;
  __syncthreads();
#pragma unroll
  for (int s = 128; s > 0; s >>= 1) {
    if (t < s) sm[t] += sm[t + s];
    __syncthreads();
  }
  if (t == 0) partial[blockIdx.x] = sm[0];
}

// B: single-block exclusive scan of the (<=256) partials
__global__ void scan_offsets_kernel(int* __restrict__ partial, int nb) {
  __shared__ int sm[256];
  int t = threadIdx.x;
  int v = (t < nb) ? partial[t] : 0;
  sm[t] = v;
  __syncthreads();
#pragma unroll
  for (int off = 1; off < 256; off <<= 1) {
    int a = (t >= off) ? sm[t - off] : 0;
    __syncthreads();
    sm[t] += a;
    __syncthreads();
  }
  if (t < nb) partial[t] = sm[t] - v;  // exclusive
}

// C: per-block inclusive scan + block offset -> rowptr/cursor
__global__ void scan_final_kernel(const int* __restrict__ deg, const int* __restrict__ partial,
                                  int* __restrict__ rowptr, int* __restrict__ cursor, int N, int E) {
  __shared__ int sm[256];
  int t = threadIdx.x;
  int i = blockIdx.x * 256 + t;
  int v = (i < N) ? deg[i] : 0;
  sm[t] = v;
  __syncthreads();
#pragma unroll
  for (int off = 1; off < 256; off <<= 1) {
    int a = (t >= off) ? sm[t - off] : 0;
    __syncthreads();
    sm[t] += a;
    __syncthreads();
  }
  if (i < N) {
    int ex = partial[blockIdx.x] + sm[t] - v;
    rowptr[i] = ex;
    cursor[i] = ex;
  }
  if (i == 0) rowptr[N] = E;
}

__global__ void scatter_build_kernel(const int* __restrict__ src, const int* __restrict__ dst,
                                     const float* __restrict__ ea, int* __restrict__ cursor,
                                     int* __restrict__ srcs, float* __restrict__ eas, int E) {
  int e = blockIdx.x * blockDim.x + threadIdx.x;
  if (e >= E) return;
  int d = dst[e];
  int pos = atomicAdd(&cursor[d], 1);
  srcs[pos] = src[e];
  eas[pos] = ea[e];
}

// ---------------- fused GATv2: alpha + softmax + aggregate + bias + relu ----------------
// One wave per node. Lane l owns channels 4l..4l+3 (head = l>>4).
// alpha_e = dot(att_h, leaky(xl[src_e] + xr[d] + ea_e*We)); no max-subtraction
// (|alpha| << 85, exp cannot overflow); out = (sum ex*xl)/(sum ex) + bias, relu.
__device__ __forceinline__ void edge_accum(const float4 xlv, const float eav,
                                           const float4 xr4, const float4 We4, const float4 at4,
                                           float4& acc, float& denom) {
  float4 v;
  v.x = fmaf(eav, We4.x, xlv.x + xr4.x);
  v.y = fmaf(eav, We4.y, xlv.y + xr4.y);
  v.z = fmaf(eav, We4.z, xlv.z + xr4.z);
  v.w = fmaf(eav, We4.w, xlv.w + xr4.w);
  v.x = (v.x >= 0.f) ? v.x : 0.2f * v.x;
  v.y = (v.y >= 0.f) ? v.y : 0.2f * v.y;
  v.z = (v.z >= 0.f) ? v.z : 0.2f * v.z;
  v.w = (v.w >= 0.f) ? v.w : 0.2f * v.w;
  float p = v.x * at4.x + v.y * at4.y + v.z * at4.z + v.w * at4.w;
  p += __shfl_xor(p, 1, 64);
  p += __shfl_xor(p, 2, 64);
  p += __shfl_xor(p, 4, 64);
  p += __shfl_xor(p, 8, 64);   // all 16 lanes of the head group hold alpha_h
  float ex = __expf(p);
  denom += ex;
  acc.x = fmaf(ex, xlv.x, acc.x);
  acc.y = fmaf(ex, xlv.y, acc.y);
  acc.z = fmaf(ex, xlv.z, acc.z);
  acc.w = fmaf(ex, xlv.w, acc.w);
}

template <bool POOL>
__global__ void gat_aggregate_kernel(const int* __restrict__ rowptr,
                                     const int* __restrict__ srcs,
                                     const float* __restrict__ eas,
                                     const float* __restrict__ xl,
                                     const float* __restrict__ xr,
                                     const float* __restrict__ We,
                                     const float* __restrict__ att,
                                     const float* __restrict__ bias,
                                     float* __restrict__ out,
                                     const int* __restrict__ batch,
                                     float* __restrict__ sums,
                                     float* __restrict__ cnt,
                                     int N) {
  int d = (int)((blockIdx.x * (size_t)blockDim.x + threadIdx.x) >> 6);
  int lane = threadIdx.x & 63;
  if (d >= N) return;
  const float4* xl4p = (const float4*)xl;
  float4 xr4 = ((const float4*)xr)[(size_t)d * 64 + lane];
  float4 We4 = ((const float4*)We)[lane];
  float4 at4 = ((const float4*)att)[lane];
  int beg = rowptr[d], end = rowptr[d + 1];
  float4 acc = {0.f, 0.f, 0.f, 0.f};
  float denom = 0.f;
  int i = beg;
  for (; i + 3 < end; i += 4) {   // 4 gathers in flight per wave (4 KB MLP)
    int s0 = srcs[i], s1 = srcs[i + 1], s2 = srcs[i + 2], s3 = srcs[i + 3];
    float e0 = eas[i], e1 = eas[i + 1], e2 = eas[i + 2], e3 = eas[i + 3];
    float4 a0 = xl4p[(size_t)s0 * 64 + lane];
    float4 a1 = xl4p[(size_t)s1 * 64 + lane];
    float4 a2 = xl4p[(size_t)s2 * 64 + lane];
    float4 a3 = xl4p[(size_t)s3 * 64 + lane];
    edge_accum(a0, e0, xr4, We4, at4, acc, denom);
    edge_accum(a1, e1, xr4, We4, at4, acc, denom);
    edge_accum(a2, e2, xr4, We4, at4, acc, denom);
    edge_accum(a3, e3, xr4, We4, at4, acc, denom);
  }
  for (; i < end; ++i) {
    int s0 = srcs[i];
    float e0 = eas[i];
    float4 a0 = xl4p[(size_t)s0 * 64 + lane];
    edge_accum(a0, e0, xr4, We4, at4, acc, denom);
  }
  float inv = 1.f / (denom + 1e-16f);
  float4 b4 = ((const float4*)bias)[lane];
  float4 o;
  o.x = fmaxf(fmaf(acc.x, inv, b4.x), 0.f);
  o.y = fmaxf(fmaf(acc.y, inv, b4.y), 0.f);
  o.z = fmaxf(fmaf(acc.z, inv, b4.z), 0.f);
  o.w = fmaxf(fmaf(acc.w, inv, b4.w), 0.f);
  if (POOL) {
    int g = batch[d];
    float* sg = sums + (size_t)g * 256 + lane * 4;
    atomicAdd(sg + 0, o.x);
    atomicAdd(sg + 1, o.y);
    atomicAdd(sg + 2, o.z);
    atomicAdd(sg + 3, o.w);
    if (lane == 0) atomicAdd(&cnt[g], 1.0f);
  } else {
    ((float4*)out)[(size_t)d * 64 + lane] = o;
  }
}

// ---------------- per-graph MLP head ----------------
__global__ void mlp_kernel(const float* __restrict__ sums, const float* __restrict__ cnt,
                           const float* __restrict__ p1W, const float* __restrict__ p1b,
                           const float* __restrict__ lng, const float* __restrict__ lnb,
                           const float* __restrict__ p2W, const float* __restrict__ p2b,
                           float* __restrict__ outp, int G) {
  __shared__ float p[256];
  __shared__ float z[128];
  __shared__ float wsum[2];
  __shared__ float wsum2[2];
  int g = blockIdx.x;
  int t = threadIdx.x;  // 0..127
  float c = fmaxf(cnt[g], 1.0f);
  p[t] = sums[(size_t)g * 256 + t] / c;
  p[t + 128] = sums[(size_t)g * 256 + t + 128] / c;
  __syncthreads();
  float acc = p1b[t];
  for (int k = 0; k < 256; ++k) acc = fmaf(p[k], p1W[k * 128 + t], acc);
  float v = acc;
#pragma unroll
  for (int off = 32; off > 0; off >>= 1) v += __shfl_xor(v, off, 64);
  if ((t & 63) == 0) wsum[t >> 6] = v;
  __syncthreads();
  float mu = (wsum[0] + wsum[1]) * (1.0f / 128.0f);
  float dv = acc - mu;
  float vv = dv * dv;
#pragma unroll
  for (int off = 32; off > 0; off >>= 1) vv += __shfl_xor(vv, off, 64);
  if ((t & 63) == 0) wsum2[t >> 6] = vv;
  __syncthreads();
  float var = (wsum2[0] + wsum2[1]) * (1.0f / 128.0f);
  float zv = dv * rsqrtf(var + 1e-5f) * lng[t] + lnb[t];
  z[t] = fmaxf(zv, 0.0f);
  __syncthreads();
  if (t < 64) {
    float o = p2b[t];
    for (int k = 0; k < 128; ++k) o = fmaf(z[k], p2W[k * 64 + t], o);
    outp[(size_t)g * 64 + t] = fmaxf(o, 0.0f);
  }
}

extern "C" void kernel_launch(void* const* d_in, const int* in_sizes, int n_in,
                              void* d_out, int out_size, void* d_ws, size_t ws_size,
                              hipStream_t stream) {
  const float* x      = (const float*)d_in[0];
  const int*   ei     = (const int*)d_in[1];
  const float* ea     = (const float*)d_in[2];
  const int*   batch  = (const int*)d_in[3];
  const float* enc_W  = (const float*)d_in[4];
  const float* enc_b  = (const float*)d_in[5];
  const float* Wl1    = (const float*)d_in[6];
  const float* bl1    = (const float*)d_in[7];
  const float* Wr1    = (const float*)d_in[8];
  const float* br1    = (const float*)d_in[9];
  const float* We1    = (const float*)d_in[10];
  const float* att1   = (const float*)d_in[11];
  const float* bias1  = (const float*)d_in[12];
  const float* Wl2    = (const float*)d_in[13];
  const float* bl2    = (const float*)d_in[14];
  const float* Wr2    = (const float*)d_in[15];
  const float* br2    = (const float*)d_in[16];
  const float* We2    = (const float*)d_in[17];
  const float* att2   = (const float*)d_in[18];
  const float* bias2  = (const float*)d_in[19];
  const float* p1W    = (const float*)d_in[20];
  const float* p1b    = (const float*)d_in[21];
  const float* lng    = (const float*)d_in[22];
  const float* lnb    = (const float*)d_in[23];
  const float* p2W    = (const float*)d_in[24];
  const float* p2b    = (const float*)d_in[25];
  float* outp = (float*)d_out;

  int N = in_sizes[0] / 8;
  int E = in_sizes[2];
  int G = out_size / 64;
  const int* src = ei;
  const int* dst = ei + E;
  int nb = (N + 255) / 256;   // scan blocks (<=256 supported; N=50000 -> 196)

  // workspace layout
  float* ws      = (float*)d_ws;
  float* h0      = ws;                         // N*64
  float* B0      = h0     + (size_t)N * 64;    // N*256 (xl)
  float* B1      = B0     + (size_t)N * 256;   // N*256 (xr)
  float* B2      = B1     + (size_t)N * 256;   // N*256 (layer1 out)
  float* eas     = B2     + (size_t)N * 256;   // E floats (sorted edge attr)
  float* sums    = eas    + (size_t)E;         // G*256
  float* cnt     = sums   + (size_t)G * 256;   // G
  int*   srcs    = (int*)(cnt + G);            // E ints (sorted src)
  int*   rowptr  = srcs + (size_t)E;           // N+1
  int*   cursor  = rowptr + (size_t)(N + 1);   // N (doubles as deg histogram)
  int*   partial = cursor + (size_t)N;         // nb

  // encoder
  encoder_kernel<<<(N * 64 + 255) / 256, 256, 0, stream>>>(x, enc_W, enc_b, h0, N);

  // CSR build (shared by both layers — dst is static)
  hipMemsetAsync(cursor, 0, (size_t)N * sizeof(int), stream);
  hist_kernel<<<(E + 255) / 256, 256, 0, stream>>>(dst, cursor, E);
  scan_partial_kernel<<<nb, 256, 0, stream>>>(cursor, partial, N);
  scan_offsets_kernel<<<1, 256, 0, stream>>>(partial, nb);
  scan_final_kernel<<<nb, 256, 0, stream>>>(cursor, partial, rowptr, cursor, N, E);
  scatter_build_kernel<<<(E + 255) / 256, 256, 0, stream>>>(src, dst, ea, cursor, srcs, eas, E);

  // GAT layer 1 (K=64): h0 -> B2
  lin_lr_kernel<64><<<(N + 7) / 8, 256, 0, stream>>>(h0, Wl1, bl1, Wr1, br1, B0, B1, N);
  gat_aggregate_kernel<false><<<(N + 3) / 4, 256, 0, stream>>>(
      rowptr, srcs, eas, B0, B1, We1, att1, bias1, B2, nullptr, nullptr, nullptr, N);

  // GAT layer 2 (K=256): B2 -> pooled sums directly
  lin_lr_kernel<256><<<(N + 7) / 8, 256, 0, stream>>>(B2, Wl2, bl2, Wr2, br2, B0, B1, N);
  hipMemsetAsync(sums, 0, ((size_t)G * 256 + G) * sizeof(float), stream);
  gat_aggregate_kernel<true><<<(N + 3) / 4, 256, 0, stream>>>(
      rowptr, srcs, eas, B0, B1, We2, att2, bias2, nullptr, batch, sums, cnt, N);

  // per-graph MLP
  mlp_kernel<<<G, 128, 0, stream>>>(sums, cnt, p1W, p1b, lng, lnb, p2W, p2b, outp, G);
}